// Round 1
// 1246.573 us; speedup vs baseline: 1.0600x; 1.0600x over previous
//
#include <hip/hip_runtime.h>
#include <math.h>

#define NTOK 8192
#define NE 16
#define DIN 1024
#define DHID 4096
#define DOUT 1024
#define MAXPAIR (NTOK * 2)
#define MAXPAD 18432          // 16384 + 16*128 worst-case padding, tile-aligned
#define MAXTILE 144           // MAXPAD/128
#define BM 128
#define BN 128
#define BK 32                 // (fallback kernel only)
#define BSTRIDE 40            // (fallback kernel only)
#define WMAGIC 0x4D6F4531

typedef __attribute__((ext_vector_type(8))) short short8;
typedef __attribute__((ext_vector_type(4))) float floatx4;

__device__ __forceinline__ unsigned short f2bf(float f) {
  unsigned int u = __float_as_uint(f);
  u += 0x7fffu + ((u >> 16) & 1u);   // round-to-nearest-even (finite data)
  return (unsigned short)(u >> 16);
}

__device__ __forceinline__ void gload_lds16(const void* g, void* l) {
  __builtin_amdgcn_global_load_lds(
      (const __attribute__((address_space(1))) void*)g,
      (__attribute__((address_space(3))) void*)l, 16, 0, 0);
}

// ---------------- init: clear counters, mark all padded rows dummy ----------------
__global__ void k_init(int* counts, int* cursor, int* pair_tok) {
  int i = blockIdx.x * 256 + threadIdx.x;
  if (i < MAXPAD) pair_tok[i] = -1;
  if (i < NE) { counts[i] = 0; cursor[i] = 0; }
}

// ---------------- gating: f64 logits, top-2 (lax.top_k tie-break), softmax ----------------
__global__ __launch_bounds__(256) void k_gating(
    const float* __restrict__ x, const float* __restrict__ Wg,
    const float* __restrict__ bg, const float* __restrict__ bias,
    float* __restrict__ out_logits, float* __restrict__ out_idx,
    int* __restrict__ topk_e, float* __restrict__ topk_w,
    int* __restrict__ counts) {
  const int lane = threadIdx.x & 63;
  const int wave = threadIdx.x >> 6;
  const int n = blockIdx.x * 4 + wave;

  double s[NE];
#pragma unroll
  for (int e = 0; e < NE; e++) s[e] = 0.0;

  for (int t = 0; t < 16; t++) {
    const int d = lane + 64 * t;
    const double xv = (double)x[(size_t)n * DIN + d];
    const float4* wrow = (const float4*)(Wg + (size_t)d * NE);
    float wr_[16];
    float4 w0 = wrow[0], w1 = wrow[1], w2 = wrow[2], w3 = wrow[3];
    wr_[0] = w0.x; wr_[1] = w0.y; wr_[2] = w0.z; wr_[3] = w0.w;
    wr_[4] = w1.x; wr_[5] = w1.y; wr_[6] = w1.z; wr_[7] = w1.w;
    wr_[8] = w2.x; wr_[9] = w2.y; wr_[10] = w2.z; wr_[11] = w2.w;
    wr_[12] = w3.x; wr_[13] = w3.y; wr_[14] = w3.z; wr_[15] = w3.w;
#pragma unroll
    for (int e = 0; e < NE; e++) s[e] += xv * (double)wr_[e];
  }
#pragma unroll
  for (int e = 0; e < NE; e++) {
    double p = s[e];
    for (int o = 32; o; o >>= 1) p += __shfl_xor(p, o, 64);
    s[e] = p + (double)bg[e];
  }

  if (lane < NE) out_logits[(size_t)n * NE + lane] = (float)s[lane];

  if (lane == 0) {
    int i1 = -1, i2 = -1;
    double m1 = -1e300, m2 = -1e300;
    for (int e = 0; e < NE; e++) {
      double v = s[e] + (double)bias[e];
      if (v > m1) { m2 = m1; i2 = i1; m1 = v; i1 = e; }
      else if (v > m2) { m2 = v; i2 = e; }
    }
    double g1 = s[i1], g2 = s[i2];
    double mm = fmax(g1, g2);
    double e1 = exp(g1 - mm), e2 = exp(g2 - mm);
    double inv = 1.0 / (e1 + e2);
    topk_e[n * 2] = i1; topk_e[n * 2 + 1] = i2;
    topk_w[n * 2] = (float)(e1 * inv); topk_w[n * 2 + 1] = (float)(e2 * inv);
    out_idx[n * 2] = (float)i1; out_idx[n * 2 + 1] = (float)i2;
    atomicAdd(&counts[i1], 1);
    atomicAdd(&counts[i2], 1);
  }
}

// ---------------- scan: padded offsets + tile->expert table ----------------
__global__ void k_scan(const int* counts, int* poff, int* tile_e) {
  if (threadIdx.x != 0 || blockIdx.x != 0) return;
  int row = 0;
  for (int e = 0; e < NE; e++) {
    poff[e] = row;
    row += ((counts[e] + BM - 1) / BM) * BM;
  }
  poff[NE] = row;
  for (int t = 0; t < MAXTILE; t++) tile_e[t] = -1;
  for (int e = 0; e < NE; e++) {
    int t0 = poff[e] / BM, t1 = poff[e + 1] / BM;
    for (int t = t0; t < t1; t++) tile_e[t] = e;
  }
}

// ---------------- placement: pair -> padded row ----------------
__global__ void k_place(const int* __restrict__ topk_e, const int* __restrict__ poff,
                        int* __restrict__ cursor, int* __restrict__ pair_tok,
                        int* __restrict__ prow) {
  int p = blockIdx.x * 256 + threadIdx.x;
  if (p >= MAXPAIR) return;
  int e = topk_e[p];
  int pos = poff[e] + atomicAdd(&cursor[e], 1);
  pair_tok[pos] = p >> 1;
  prow[p] = pos;
}

// ---------------- gather x rows -> bf16 (optionally granule-swizzled), zeros for dummies ----------------
// SWZ: 16B granule g of row r stored at position (g&~7)|((g&7)^((r>>1)&7)).
template <bool SWZ>
__global__ __launch_bounds__(256) void k_gather(const float* __restrict__ x,
                                                const int* __restrict__ pair_tok,
                                                unsigned short* __restrict__ xg) {
  const int row = blockIdx.x;
  const int tok = pair_tok[row];
  const int t = threadIdx.x;
  const int c = t * 4;
  int cs = c;
  if (SWZ) {
    const int g = c >> 3;
    const int p = (g & ~7) | ((g & 7) ^ ((row >> 1) & 7));
    cs = p * 8 + (c & 7);
  }
  unsigned short* dst = xg + (size_t)row * DIN + cs;
  if (tok < 0) {
    uint2 z; z.x = 0; z.y = 0;
    *(uint2*)dst = z;
  } else {
    const float4 v = *(const float4*)(x + (size_t)tok * DIN + c);
    uint2 pk;
    pk.x = (unsigned)f2bf(v.x) | ((unsigned)f2bf(v.y) << 16);
    pk.y = (unsigned)f2bf(v.z) | ((unsigned)f2bf(v.w) << 16);
    *(uint2*)dst = pk;
  }
}

// ---------------- weight transpose+convert: W[e][k][n] f32 -> Wt[e][n][k] bf16, swizzled ----------------
// Flag-guarded: skips if workspace still holds converted weights from a prior replay.
#define WCS 66   // LDS row stride in ushorts (33 dwords) — spreads banks for column reads
__global__ __launch_bounds__(256) void k_wconv(const float* __restrict__ W,
                                               unsigned short* __restrict__ Wt,
                                               const int* __restrict__ wflag,
                                               const int K, const int N) {
  if (wflag[0] == WMAGIC) return;
  __shared__ unsigned short Ls[64 * WCS];
  const int t = threadIdx.x;
  const int e = blockIdx.z;
  const int k0 = blockIdx.x * 64;
  const int n0 = blockIdx.y * 64;
  const float* src = W + ((size_t)e * K + k0) * N + n0;
#pragma unroll
  for (int i = 0; i < 4; i++) {
    const int kl = (t >> 4) + i * 16;
    const int nl = (t & 15) * 4;
    const float4 v = *(const float4*)(src + (size_t)kl * N + nl);
    unsigned* d = (unsigned*)(Ls + kl * WCS + nl);
    d[0] = (unsigned)f2bf(v.x) | ((unsigned)f2bf(v.y) << 16);
    d[1] = (unsigned)f2bf(v.z) | ((unsigned)f2bf(v.w) << 16);
  }
  __syncthreads();
  const int lane = t & 63, wave = t >> 6;
  const int g = lane & 7;        // output granule (8 k's)
  const int ns = lane >> 3;      // n-sub within wave: 8 rows -> 128B contiguous per row
#pragma unroll
  for (int p = 0; p < 2; p++) {
    const int nl = p * 32 + wave * 8 + ns;
    const int n = n0 + nl;
    short8 vv;
#pragma unroll
    for (int j = 0; j < 8; j++) vv[j] = (short)Ls[(g * 8 + j) * WCS + nl];
    const int pl = g ^ ((n >> 1) & 7);   // swizzled granule position within 128B window
    *(short8*)(Wt + ((size_t)e * N + n) * K + k0 + pl * 8) = vv;
  }
}

__global__ void k_setflag(int* wflag) { wflag[0] = WMAGIC; }

// ---------------- fast GEMM: bf16 A (swizzled) x bf16 Bt (transposed, swizzled) ----------------
// C[row][n] = act(A[row][:] @ Bt[e][n][:] + bias[e][n]); 128x128 tile, BK=64, both
// operands staged via global_load_lds (linear dst, pre-swizzled global source).
template <int K, int N, bool BF16RELU>
__global__ __launch_bounds__(256, 3) void k_gemm_bf(
    const unsigned short* __restrict__ A, const unsigned short* __restrict__ Bt,
    const float* __restrict__ bias, const int* __restrict__ tile_e,
    void* __restrict__ Cout) {
  const int e = tile_e[blockIdx.y];
  if (e < 0) return;
  const int row0 = blockIdx.y * BM;
  const int col0 = blockIdx.x * BN;

  __shared__ unsigned short As[BM * 64];   // 16 KB [128 rows][64 k], granule-swizzled
  __shared__ unsigned short Bs[BN * 64];   // 16 KB [128 n   ][64 k], granule-swizzled

  const int tid = threadIdx.x;
  const int lane = tid & 63;
  const int wave = tid >> 6;
  const int m16 = lane & 15;
  const int q = lane >> 4;
  const int wr = (wave >> 1) * 64;
  const int wc = (wave & 1) * 64;

  const unsigned short* Abase = A + (size_t)row0 * K;
  const unsigned short* Bbase = Bt + ((size_t)e * N + col0) * K;

  // staging addresses: granule gi=(wave*4+it)*64+lane -> row gi>>3, linear slot gi&7
  const unsigned short* asrc[4];
  const unsigned short* bsrc[4];
  unsigned short* adst[4];
  unsigned short* bdst[4];
#pragma unroll
  for (int it = 0; it < 4; it++) {
    const int gi = (wave * 4 + it) * 64 + lane;
    const int r = gi >> 3, sl = gi & 7;
    asrc[it] = Abase + (size_t)r * K + sl * 8;
    bsrc[it] = Bbase + (size_t)r * K + sl * 8;
    adst[it] = As + (wave * 4 + it) * 512;
    bdst[it] = Bs + (wave * 4 + it) * 512;
  }

  // fragment read constants: row byte-base and 3-bit row swizzle
  int ra[4], sa[4], rb[4], sb[4];
#pragma unroll
  for (int i = 0; i < 4; i++) {
    const int r1 = wr + i * 16 + m16;
    ra[i] = r1 * 64; sa[i] = (r1 >> 1) & 7;
    const int r2 = wc + i * 16 + m16;
    rb[i] = r2 * 64; sb[i] = (r2 >> 1) & 7;
  }

  floatx4 acc[4][4] = {};

  for (int kt = 0; kt < K; kt += 64) {
#pragma unroll
    for (int it = 0; it < 4; it++) gload_lds16((const void*)(asrc[it] + kt), (void*)adst[it]);
#pragma unroll
    for (int it = 0; it < 4; it++) gload_lds16((const void*)(bsrc[it] + kt), (void*)bdst[it]);
    __syncthreads();
#pragma unroll
    for (int kk = 0; kk < 2; kk++) {
      const int gq = kk * 4 + q;
      short8 af[4], bfv[4];
#pragma unroll
      for (int i = 0; i < 4; i++) af[i] = *(const short8*)(As + ra[i] + (gq ^ sa[i]) * 8);
#pragma unroll
      for (int j = 0; j < 4; j++) bfv[j] = *(const short8*)(Bs + rb[j] + (gq ^ sb[j]) * 8);
#pragma unroll
      for (int i = 0; i < 4; i++)
#pragma unroll
        for (int j = 0; j < 4; j++)
          acc[i][j] = __builtin_amdgcn_mfma_f32_16x16x32_bf16(af[i], bfv[j], acc[i][j], 0, 0, 0);
    }
    __syncthreads();
  }

  // epilogue: C/D layout col=lane&15, row=(lane>>4)*4+reg
#pragma unroll
  for (int i = 0; i < 4; i++) {
#pragma unroll
    for (int j = 0; j < 4; j++) {
      const int gc = col0 + wc + j * 16 + m16;
      const float bb = bias[(size_t)e * N + gc];
#pragma unroll
      for (int r = 0; r < 4; r++) {
        const int gr = row0 + wr + i * 16 + q * 4 + r;
        float v = acc[i][j][r] + bb;
        if constexpr (BF16RELU) {
          v = fmaxf(v, 0.0f);
          const int g = gc >> 3;
          const int p = (g & ~7) | ((g & 7) ^ ((gr >> 1) & 7));  // h rows swizzled for GEMM2
          ((unsigned short*)Cout)[(size_t)gr * N + p * 8 + (gc & 7)] = f2bf(v);
        } else {
          ((float*)Cout)[(size_t)gr * N + gc] = v;
        }
      }
    }
  }
}

// ---------------- fallback GEMM (previous verified kernel): f32 B staging ----------------
template <int K, int N, bool BF16RELU>
__global__ __launch_bounds__(256, 3) void k_gemm_f32(
    const unsigned short* __restrict__ A, const float* __restrict__ Bw,
    const float* __restrict__ bias, const int* __restrict__ tile_e,
    void* __restrict__ Cout) {
  const int e = tile_e[blockIdx.y];
  if (e < 0) return;
  const int row0 = blockIdx.y * BM;
  const int col0 = blockIdx.x * BN;

  __shared__ unsigned short As[BM * BK];
  __shared__ unsigned short Bs[BN * BSTRIDE];

  const int tid = threadIdx.x;
  const int lane = tid & 63;
  const int wave = tid >> 6;
  const int m16 = lane & 15;
  const int q = lane >> 4;
  const int wr = (wave >> 1) * 64;
  const int wc = (wave & 1) * 64;

  const unsigned short* Abase = A + (size_t)row0 * K;
  const int bn = tid & 127;
  const int bkh = tid >> 7;
  const float* Bbase = Bw + (size_t)e * K * N + (size_t)col0 + bn;

  floatx4 acc[4][4] = {};

  for (int kt = 0; kt < K; kt += BK) {
#pragma unroll
    for (int it = 0; it < 2; it++) {
      const int c = wave * 2 + it;
      const unsigned short* g =
          Abase + (size_t)(c * 16 + (lane >> 2)) * K + kt + (lane & 3) * 8;
      gload_lds16((const void*)g, (void*)(As + c * 512));
    }
    {
      const float* bp = Bbase + (size_t)(kt + bkh * 16) * N;
      float bv[16];
#pragma unroll
      for (int j = 0; j < 16; j++) bv[j] = bp[(size_t)j * N];
      short8 w0, w1;
#pragma unroll
      for (int j = 0; j < 8; j++) {
        w0[j] = (short)f2bf(bv[j]);
        w1[j] = (short)f2bf(bv[j + 8]);
      }
      short8* dst = (short8*)(Bs + bn * BSTRIDE + bkh * 16);
      dst[0] = w0;
      dst[1] = w1;
    }
    __syncthreads();
    short8 af[4], bfr[4];
#pragma unroll
    for (int i = 0; i < 4; i++)
      af[i] = *(const short8*)(As + (wr + i * 16 + m16) * BK + q * 8);
#pragma unroll
    for (int j = 0; j < 4; j++)
      bfr[j] = *(const short8*)(Bs + (wc + j * 16 + m16) * BSTRIDE + q * 8);
#pragma unroll
    for (int i = 0; i < 4; i++)
#pragma unroll
      for (int j = 0; j < 4; j++)
        acc[i][j] = __builtin_amdgcn_mfma_f32_16x16x32_bf16(af[i], bfr[j], acc[i][j], 0, 0, 0);
    __syncthreads();
  }

#pragma unroll
  for (int i = 0; i < 4; i++) {
#pragma unroll
    for (int j = 0; j < 4; j++) {
      const int gc = col0 + wc + j * 16 + m16;
      const float bb = bias[(size_t)e * N + gc];
#pragma unroll
      for (int r = 0; r < 4; r++) {
        const int gr = row0 + wr + i * 16 + q * 4 + r;
        float v = acc[i][j][r] + bb;
        if constexpr (BF16RELU) {
          v = fmaxf(v, 0.0f);
          ((unsigned short*)Cout)[(size_t)gr * N + gc] = f2bf(v);
        } else {
          ((float*)Cout)[(size_t)gr * N + gc] = v;
        }
      }
    }
  }
}

// ---------------- combine: final = w0*y[p0] + w1*y[p1] ----------------
__global__ __launch_bounds__(256) void k_combine(const float* __restrict__ y,
                                                 const int* __restrict__ prow,
                                                 const float* __restrict__ topk_w,
                                                 float* __restrict__ out) {
  const int n = blockIdx.x;
  const int c = threadIdx.x * 4;
  const int p0 = prow[n * 2], p1 = prow[n * 2 + 1];
  const float w0 = topk_w[n * 2], w1 = topk_w[n * 2 + 1];
  const float4 a = *(const float4*)(y + (size_t)p0 * DOUT + c);
  const float4 b = *(const float4*)(y + (size_t)p1 * DOUT + c);
  float4 o;
  o.x = w0 * a.x + w1 * b.x;
  o.y = w0 * a.y + w1 * b.y;
  o.z = w0 * a.z + w1 * b.z;
  o.w = w0 * a.w + w1 * b.w;
  *(float4*)(out + (size_t)n * DOUT + c) = o;
}

extern "C" void kernel_launch(void* const* d_in, const int* in_sizes, int n_in,
                              void* d_out, int out_size, void* d_ws, size_t ws_size,
                              hipStream_t stream) {
  (void)in_sizes; (void)n_in; (void)out_size;
  const float* x = (const float*)d_in[0];
  const float* Wg = (const float*)d_in[1];
  const float* bg = (const float*)d_in[2];
  const float* W1 = (const float*)d_in[3];
  const float* b1 = (const float*)d_in[4];
  const float* W2 = (const float*)d_in[5];
  const float* b2 = (const float*)d_in[6];
  const float* bias = (const float*)d_in[7];

  float* out_final = (float*)d_out;                          // [8192][1024]
  float* out_logits = out_final + (size_t)NTOK * DOUT;       // [8192][16]
  float* out_idx = out_logits + (size_t)NTOK * NE;           // [8192][2] as float

  char* ws = (char*)d_ws;
  size_t off = 0;
  auto alloc = [&](size_t b) {
    void* p = ws + off;
    off = (off + b + 255) & ~(size_t)255;
    return p;
  };
  int* wflag = (int*)alloc(4);
  int* counts = (int*)alloc(NE * 4);
  int* cursor = (int*)alloc(NE * 4);
  int* poff = (int*)alloc((NE + 1) * 4);
  int* tile_e = (int*)alloc(MAXTILE * 4);
  int* topk_e = (int*)alloc(MAXPAIR * 4);
  float* topk_w = (float*)alloc(MAXPAIR * 4);
  int* pair_tok = (int*)alloc(MAXPAD * 4);
  int* prow = (int*)alloc(MAXPAIR * 4);
  unsigned short* xg = (unsigned short*)alloc((size_t)MAXPAD * DIN * 2);   // 36.9 MB
  unsigned short* h = (unsigned short*)alloc((size_t)MAXPAD * DHID * 2);   // 151 MB
  float* y = (float*)alloc((size_t)MAXPAD * DOUT * 4);                     // 75.5 MB
  unsigned short* W1t = (unsigned short*)alloc((size_t)NE * DIN * DHID * 2);   // 134 MB
  unsigned short* W2t = (unsigned short*)alloc((size_t)NE * DHID * DOUT * 2);  // 134 MB
  const bool fast = (off <= ws_size);

  k_init<<<(MAXPAD + 255) / 256, 256, 0, stream>>>(counts, cursor, pair_tok);
  k_gating<<<NTOK / 4, 256, 0, stream>>>(x, Wg, bg, bias, out_logits, out_idx,
                                         topk_e, topk_w, counts);
  k_scan<<<1, 1, 0, stream>>>(counts, poff, tile_e);
  k_place<<<MAXPAIR / 256, 256, 0, stream>>>(topk_e, poff, cursor, pair_tok, prow);

  if (fast) {
    k_wconv<<<dim3(DIN / 64, DHID / 64, NE), 256, 0, stream>>>(W1, W1t, wflag, DIN, DHID);
    k_wconv<<<dim3(DHID / 64, DOUT / 64, NE), 256, 0, stream>>>(W2, W2t, wflag, DHID, DOUT);
    k_setflag<<<1, 1, 0, stream>>>(wflag);
    k_gather<true><<<MAXPAD, 256, 0, stream>>>(x, pair_tok, xg);
    k_gemm_bf<DIN, DHID, true><<<dim3(DHID / BN, MAXTILE), 256, 0, stream>>>(
        xg, W1t, b1, tile_e, (void*)h);
    k_gemm_bf<DHID, DOUT, false><<<dim3(DOUT / BN, MAXTILE), 256, 0, stream>>>(
        h, W2t, b2, tile_e, (void*)y);
  } else {
    k_gather<false><<<MAXPAD, 256, 0, stream>>>(x, pair_tok, xg);
    k_gemm_f32<DIN, DHID, true><<<dim3(DHID / BN, MAXTILE), 256, 0, stream>>>(
        xg, W1, b1, tile_e, (void*)h);
    k_gemm_f32<DHID, DOUT, false><<<dim3(DOUT / BN, MAXTILE), 256, 0, stream>>>(
        h, W2, b2, tile_e, (void*)y);
  }
  k_combine<<<NTOK, 256, 0, stream>>>(y, prow, topk_w, out_final);
}